// Round 11
// baseline (644.376 us; speedup 1.0000x reference)
//
#include <hip/hip_runtime.h>

#define N_NODES 50000
#define N_EDGES 800000
#define D_IN    64
#define D_HID   128
#define NBLK    ((N_NODES + 255) / 256)   // 196
#define NODEB   (N_NODES / 4)             // 12500 blocks x 4 waves

__device__ __forceinline__ float blo(unsigned r) { return __uint_as_float(r << 16); }
__device__ __forceinline__ float bhi(unsigned r) { return __uint_as_float(r & 0xFFFF0000u); }
__device__ __forceinline__ unsigned short f2bf(float f) {
    unsigned u = __float_as_uint(f);
    return (unsigned short)((u + 0x7FFFu + ((u >> 16) & 1u)) >> 16);
}

// ---- CSR build ----
__global__ void k_count(const int* __restrict__ rcv, int* __restrict__ deg) {
    int i = blockIdx.x * blockDim.x + threadIdx.x;
    if (i < N_EDGES) atomicAdd(&deg[rcv[i]], 1);
}

__global__ void k_blocksum(const int* __restrict__ deg, int* __restrict__ bsum) {
    int b = blockIdx.x, t = threadIdx.x;
    int i = b * 256 + t;
    int v = (i < N_NODES) ? deg[i] : 0;
#pragma unroll
    for (int o = 32; o >= 1; o >>= 1) v += __shfl_down(v, o);
    __shared__ int s[4];
    if ((t & 63) == 0) s[t >> 6] = v;
    __syncthreads();
    if (t == 0) bsum[b] = s[0] + s[1] + s[2] + s[3];
}

__global__ void k_scanb(const int* __restrict__ bsum, int* __restrict__ boff) {
    __shared__ int sh[256];
    int t = threadIdx.x;
    int v = (t < NBLK) ? bsum[t] : 0;
    sh[t] = v;
    __syncthreads();
    for (int d = 1; d < 256; d <<= 1) {
        int u = (t >= d) ? sh[t - d] : 0;
        __syncthreads();
        sh[t] += u;
        __syncthreads();
    }
    boff[t] = sh[t] - v;   // exclusive
}

__global__ void k_offsets(const int* __restrict__ deg, const int* __restrict__ boff,
                          int* __restrict__ off, int* __restrict__ cursor,
                          float* __restrict__ inv) {
    __shared__ int sh[256];
    int b = blockIdx.x, t = threadIdx.x, i = b * 256 + t;
    int d = (i < N_NODES) ? deg[i] : 0;
    sh[t] = d;
    __syncthreads();
    for (int o = 1; o < 256; o <<= 1) {
        int u = (t >= o) ? sh[t - o] : 0;
        __syncthreads();
        sh[t] += u;
        __syncthreads();
    }
    if (i < N_NODES) {
        int excl = boff[b] + sh[t] - d;
        off[i] = excl;
        cursor[i] = excl;
        inv[i] = d > 0 ? 1.0f / (float)d : 0.0f;
    }
    if (b == 0 && t == 0) off[N_NODES] = N_EDGES;
}

__global__ void k_fill(const int* __restrict__ snd, const int* __restrict__ rcv,
                       const float* __restrict__ w,
                       int* __restrict__ cursor, int2* __restrict__ e_sw) {
    int i = blockIdx.x * blockDim.x + threadIdx.x;
    if (i >= N_EDGES) return;
    int r = rcv[i];
    int p = atomicAdd(&cursor[r], 1);
    e_sw[p] = make_int2(snd[i], __float_as_int(w[i]));
}

// ---- fp32 -> bf16 pair-packed (separate pass; fusing raced in r9) ----
__global__ void k_tobf(const float* __restrict__ src, unsigned int* __restrict__ dst,
                       int npairs) {
    int i = blockIdx.x * blockDim.x + threadIdx.x;
    if (i >= npairs) return;
    float2 v = *(const float2*)(src + (size_t)i * 2);
    dst[i] = (unsigned)f2bf(v.x) | ((unsigned)f2bf(v.y) << 16);
}

// ---- fused layer: 16-lanes-per-edge gather + residual (+ MLP) ----
// One wave per node; group g=lane>>4 handles edges e+g; lane m=lane&15 loads
// 16B (D=128, uint4 = feats 8m..8m+7) or 8B (D=64, uint2 = feats 4m..4m+3)
// of the sender row -> one vmem instruction = 4 full rows. Descriptors read
// directly per-lane (contiguous, coalesced; NO shfl in the address chain —
// r10 lesson). Unroll-2 -> 8 edges in flight. Group partials combined by
// shfl_xor(16/32) once per node.
template<int DIN, bool RELU, bool DO_MLP>
__global__ __launch_bounds__(256) void k_layer(
        const float* __restrict__ h,             // fp32 rows (residual)
        const unsigned* __restrict__ hbw,        // bf16 rows, pair-packed
        const int* __restrict__ off,
        const int2* __restrict__ e_sw,
        const float* __restrict__ inv,
        const float* __restrict__ eps, int li,
        const float* __restrict__ W,
        const float* __restrict__ b,
        float* __restrict__ out) {
    constexpr int NF = DIN / 16;                 // feats per lane (8 or 4)
    int wave = threadIdx.x >> 6;
    int lane = threadIdx.x & 63;
    int g    = lane >> 4;
    int m    = lane & 15;
    int n = blockIdx.x * 4 + wave;               // NODEB*4 == N_NODES

    int e0 = off[n], e1 = off[n + 1];
    float pl[NF];
#pragma unroll
    for (int j = 0; j < NF; ++j) pl[j] = 0.0f;

    int e = e0;
    if constexpr (DIN == 128) {
        const uint4* rows = (const uint4*)hbw;   // 16 uint4 per row
        for (; e + 8 <= e1; e += 8) {            // 2 x (desc + rowx4) in flight
            int2 sa = e_sw[e + g];
            int2 sb = e_sw[e + 4 + g];
            uint4 ra = rows[(size_t)sa.x * 16 + m];
            uint4 rb = rows[(size_t)sb.x * 16 + m];
            float wa = __int_as_float(sa.y), wb = __int_as_float(sb.y);
            pl[0] += blo(ra.x) * wa + blo(rb.x) * wb;
            pl[1] += bhi(ra.x) * wa + bhi(rb.x) * wb;
            pl[2] += blo(ra.y) * wa + blo(rb.y) * wb;
            pl[3] += bhi(ra.y) * wa + bhi(rb.y) * wb;
            pl[4] += blo(ra.z) * wa + blo(rb.z) * wb;
            pl[5] += bhi(ra.z) * wa + bhi(rb.z) * wb;
            pl[6] += blo(ra.w) * wa + blo(rb.w) * wb;
            pl[7] += bhi(ra.w) * wa + bhi(rb.w) * wb;
        }
        for (; e < e1; e += 4) {                 // clamped tail
            int ee = e + g;
            bool v = ee < e1;
            int2 sw = e_sw[v ? ee : e1 - 1];
            float w = v ? __int_as_float(sw.y) : 0.0f;
            uint4 r = rows[(size_t)sw.x * 16 + m];
            pl[0] += blo(r.x) * w; pl[1] += bhi(r.x) * w;
            pl[2] += blo(r.y) * w; pl[3] += bhi(r.y) * w;
            pl[4] += blo(r.z) * w; pl[5] += bhi(r.z) * w;
            pl[6] += blo(r.w) * w; pl[7] += bhi(r.w) * w;
        }
    } else {                                     // DIN == 64
        const uint2* rows = (const uint2*)hbw;   // 16 uint2 per row
        for (; e + 8 <= e1; e += 8) {
            int2 sa = e_sw[e + g];
            int2 sb = e_sw[e + 4 + g];
            uint2 ra = rows[(size_t)sa.x * 16 + m];
            uint2 rb = rows[(size_t)sb.x * 16 + m];
            float wa = __int_as_float(sa.y), wb = __int_as_float(sb.y);
            pl[0] += blo(ra.x) * wa + blo(rb.x) * wb;
            pl[1] += bhi(ra.x) * wa + bhi(rb.x) * wb;
            pl[2] += blo(ra.y) * wa + blo(rb.y) * wb;
            pl[3] += bhi(ra.y) * wa + bhi(rb.y) * wb;
        }
        for (; e < e1; e += 4) {
            int ee = e + g;
            bool v = ee < e1;
            int2 sw = e_sw[v ? ee : e1 - 1];
            float w = v ? __int_as_float(sw.y) : 0.0f;
            uint2 r = rows[(size_t)sw.x * 16 + m];
            pl[0] += blo(r.x) * w; pl[1] += bhi(r.x) * w;
            pl[2] += blo(r.y) * w; pl[3] += bhi(r.y) * w;
        }
    }

    // combine the 4 groups' partials -> every lane holds feats NF*m..NF*m+NF-1
#pragma unroll
    for (int j = 0; j < NF; ++j) {
        pl[j] += __shfl_xor(pl[j], 16);
        pl[j] += __shfl_xor(pl[j], 32);
    }

    float se = 1.0f + eps[li];
    se = se > 0.0f ? se : 0.0f;                  // relu(1+eps)
    float id = inv[n];

    float pre[NF];
    if constexpr (DIN == 128) {
        const float4* h4 = (const float4*)(h + (size_t)n * 128);
        float4 hv0 = h4[2 * m], hv1 = h4[2 * m + 1];
        pre[0] = hv0.x * se + pl[0] * id;  pre[1] = hv0.y * se + pl[1] * id;
        pre[2] = hv0.z * se + pl[2] * id;  pre[3] = hv0.w * se + pl[3] * id;
        pre[4] = hv1.x * se + pl[4] * id;  pre[5] = hv1.y * se + pl[5] * id;
        pre[6] = hv1.z * se + pl[6] * id;  pre[7] = hv1.w * se + pl[7] * id;
    } else {
        const float4* h4 = (const float4*)(h + (size_t)n * 64);
        float4 hv = h4[m];
        pre[0] = hv.x * se + pl[0] * id;   pre[1] = hv.y * se + pl[1] * id;
        pre[2] = hv.z * se + pl[2] * id;   pre[3] = hv.w * se + pl[3] * id;
    }

    if constexpr (!DO_MLP) {
        if (g == 0) {                            // 16 lanes write the row
            float4* o4 = (float4*)(out + (size_t)n * DIN);
            if constexpr (DIN == 128) {
                o4[2 * m]     = make_float4(pre[0], pre[1], pre[2], pre[3]);
                o4[2 * m + 1] = make_float4(pre[4], pre[5], pre[6], pre[7]);
            } else {
                o4[m] = make_float4(pre[0], pre[1], pre[2], pre[3]);
            }
        }
        return;
    }

    // MLP: DIN -> 128; out cols {2l, 2l+1}; feat d lives in lane d/NF elem d%NF
    float2 acc = ((const float2*)b)[lane];
#pragma unroll
    for (int d = 0; d < DIN; ++d) {
        float pd;
        if constexpr (DIN == 128) pd = __shfl(pre[d & 7], d >> 3);
        else                      pd = __shfl(pre[d & 3], d >> 2);
        float2 wv = ((const float2*)(W + (size_t)d * 128))[lane];
        acc.x += pd * wv.x;
        acc.y += pd * wv.y;
    }
    if (RELU) {
        acc.x = acc.x > 0.0f ? acc.x : 0.0f;
        acc.y = acc.y > 0.0f ? acc.y : 0.0f;
    }
    ((float2*)(out + (size_t)n * 128))[lane] = acc;
}

// ---- final standalone MLP (layer-2 tail; proven in r10) ----
__global__ __launch_bounds__(256) void k_mlp(const float* __restrict__ pre,
                                             const float* __restrict__ W,
                                             const float* __restrict__ b,
                                             float* __restrict__ out) {
    int wave = threadIdx.x >> 6;
    int lane = threadIdx.x & 63;
    int n = blockIdx.x * 4 + wave;

    float2 p = ((const float2*)(pre + (size_t)n * 128))[lane];
    float2 acc = ((const float2*)b)[lane];
#pragma unroll
    for (int d = 0; d < 128; ++d) {
        float pd = __shfl((d & 1) ? p.y : p.x, d >> 1);
        float2 wv = ((const float2*)(W + (size_t)d * 128))[lane];
        acc.x += pd * wv.x;
        acc.y += pd * wv.y;
    }
    ((float2*)(out + (size_t)n * 128))[lane] = acc;
}

extern "C" void kernel_launch(void* const* d_in, const int* in_sizes, int n_in,
                              void* d_out, int out_size, void* d_ws, size_t ws_size,
                              hipStream_t stream) {
    const float* h0  = (const float*)d_in[0];
    const float* wts = (const float*)d_in[1];
    const int*   snd = (const int*)d_in[2];
    const int*   rcv = (const int*)d_in[3];
    const float* W0  = (const float*)d_in[4];
    const float* b0  = (const float*)d_in[5];
    const float* W1  = (const float*)d_in[6];
    const float* b1  = (const float*)d_in[7];
    const float* W2  = (const float*)d_in[8];
    const float* b2  = (const float*)d_in[9];
    const float* eps = (const float*)d_in[10];

    float* out0 = (float*)d_out;                  // final: node_embeddings
    float* out1 = out0 + (size_t)N_NODES * D_HID; // final: h

    // ws (~20.5 MB): deg|bsum|boff|off|cursor|inv | e_sw(int2) | pad | hbw
    int*   deg    = (int*)d_ws;
    int*   bsum   = deg + N_NODES;
    int*   boff   = bsum + 256;
    int*   off    = boff + 256;
    int*   cursor = off + N_NODES + 2;            // keeps e_sw 8B-aligned
    float* inv    = (float*)(cursor + N_NODES);
    int2*  e_sw   = (int2*)(inv + N_NODES);
    unsigned* hbw = (unsigned*)(e_sw + N_EDGES) + 2;  // +2 -> 16B-aligned for uint4

    hipMemsetAsync(deg, 0, (size_t)N_NODES * sizeof(int), stream);
    k_count<<<(N_EDGES + 255) / 256, 256, 0, stream>>>(rcv, deg);
    k_blocksum<<<NBLK, 256, 0, stream>>>(deg, bsum);
    k_scanb<<<1, 256, 0, stream>>>(bsum, boff);
    k_offsets<<<NBLK, 256, 0, stream>>>(deg, boff, off, cursor, inv);
    k_fill<<<(N_EDGES + 255) / 256, 256, 0, stream>>>(snd, rcv, wts, cursor, e_sw);

    // L0: tobf(h0) ; gather(h0)+mlp0 -> out0 (= h1)
    k_tobf<<<(N_NODES * D_IN / 2 + 255) / 256, 256, 0, stream>>>(
        h0, hbw, N_NODES * D_IN / 2);
    k_layer<D_IN, true, true><<<NODEB, 256, 0, stream>>>(
        h0, hbw, off, e_sw, inv, eps, 0, W0, b0, out0);

    // L1: tobf(h1) ; gather(h1)+mlp1 -> out1 (= h2)
    k_tobf<<<(N_NODES * D_HID / 2 + 255) / 256, 256, 0, stream>>>(
        out0, hbw, N_NODES * D_HID / 2);
    k_layer<D_HID, true, true><<<NODEB, 256, 0, stream>>>(
        out0, hbw, off, e_sw, inv, eps, 1, W1, b1, out1);

    // L2a: tobf(h2) ; gather(h2) -> out0 (= node_embeddings)
    k_tobf<<<(N_NODES * D_HID / 2 + 255) / 256, 256, 0, stream>>>(
        out1, hbw, N_NODES * D_HID / 2);
    k_layer<D_HID, false, false><<<NODEB, 256, 0, stream>>>(
        out1, hbw, off, e_sw, inv, eps, 2, nullptr, nullptr, out0);

    // L2b: final MLP (no relu): out0 -> out1
    k_mlp<<<NODEB, 256, 0, stream>>>(out0, W2, b2, out1);
}